// Round 1
// baseline (356.257 us; speedup 1.0000x reference)
//
#include <hip/hip_runtime.h>
#include <hip/hip_bf16.h>

#define HDIM 128
#define CDIM 8
#define SCAN_CHUNK 4096   // 256 threads x 16 elements

// Harness contract (pinned empirically, rounds 1-3):
//   float32 tensors -> const float* ; int64 edge_index -> const int* ; output -> float*
//
// R12: agg was latency-bound (VALUBusy 51%, HBM 14%, occ 31%, MLP ~4/wave,
// register pipeline capped by 64-VGPR cliff). Rebuild agg as async
// global_load_lds pipeline: CSR padded to 16-slot chunks (self-loop = slot 0,
// pad = (src 0, w 0)), per chunk 1x width-4 strip load + 4x width-16 row
// gathers into per-wave LDS ring, counted vmcnt(4/5) steady state (T3/T4
// pattern). 9 VMEM in flight/wave, zero VGPR cost, LDS becomes the occupancy
// binder (3 blk/CU agg_gemm, 4 blk/CU agg_fc).

#define WLDS  8960        // per-wave LDS: 2*4096B row ring + 3*256B strip ring
#define RINGB 8192

__device__ __forceinline__ void vm_wait0() { asm volatile("s_waitcnt vmcnt(0)" ::: "memory"); }
__device__ __forceinline__ void vm_wait4() { asm volatile("s_waitcnt vmcnt(4)" ::: "memory"); }
__device__ __forceinline__ void vm_wait5() { asm volatile("s_waitcnt vmcnt(5)" ::: "memory"); }

__device__ __forceinline__ void gld_lds16(const void* g, void* s) {
    __builtin_amdgcn_global_load_lds((const __attribute__((address_space(1))) void*)g,
                                     (__attribute__((address_space(3))) void*)s, 16, 0, 0);
}
__device__ __forceinline__ void gld_lds4(const void* g, void* s) {
    __builtin_amdgcn_global_load_lds((const __attribute__((address_space(1))) void*)g,
                                     (__attribute__((address_space(3))) void*)s, 4, 0, 0);
}

// ---------- histogram ----------
__global__ void k_hist(const int* __restrict__ col, int* __restrict__ cnt, int E) {
    int e = blockIdx.x * blockDim.x + threadIdx.x;
    if (e < E) atomicAdd(&cnt[col[e]], 1);
}

// ---------- single-launch decoupled-lookback scan over PADDED slot counts ----------
// slots(i) = ceil((deg+1)/16)*16  (self-loop included). Writes self slot
// srcW[pptr[i]] = (i, dinv_i); cursor starts at pptr[i]+1; pad slots stay the
// memset'd (0, 0.0f) = row-0 gather with weight 0 (exact no-op).
__global__ __launch_bounds__(256) void k_scan(const int* __restrict__ cnt,
                                              int* __restrict__ status,
                                              int* __restrict__ ptr,
                                              int* __restrict__ cursor,
                                              float* __restrict__ dinv,
                                              int2* __restrict__ srcW,
                                              int n) {
    int b = blockIdx.x, tid = threadIdx.x;
    int base = b * SCAN_CHUNK + tid * 16;
    int v[16], sl[16];
    int s = 0;
#pragma unroll
    for (int j = 0; j < 16; j++) {
        int i = base + j;
        v[j]  = (i < n) ? cnt[i] : 0;
        sl[j] = (i < n) ? ((v[j] + 16) & ~15) : 0;   // ceil((deg+1)/16)*16
        s += sl[j];
    }
    int lane = tid & 63, wid = tid >> 6;
    int x = s;
    for (int off = 1; off < 64; off <<= 1) {
        int y = __shfl_up(x, off, 64);
        if (lane >= off) x += y;
    }
    __shared__ int wtot[4];
    __shared__ int sprefix;
    if (lane == 63) wtot[wid] = x;
    __syncthreads();
    if (tid == 0) {
        int tot = wtot[0] + wtot[1] + wtot[2] + wtot[3];
        atomicExch(&status[b], tot + 1);            // publish first (no peer deadlock)
        int pre = 0;
        for (int p = 0; p < b; p++) {
            int vv;
            do { vv = atomicAdd(&status[p], 0); } while (vv == 0);
            pre += vv - 1;
        }
        sprefix = pre;
    }
    __syncthreads();
    int woff = 0;
    for (int w = 0; w < wid; w++) woff += wtot[w];
    int excl = sprefix + woff + (x - s);
#pragma unroll
    for (int j = 0; j < 16; j++) {
        int i = base + j;
        if (i < n) {
            ptr[i] = excl;
            cursor[i] = excl + 1;                    // slot 0 = self-loop
            float di = rsqrtf((float)v[j] + 1.0f);
            dinv[i] = di;
            srcW[excl] = make_int2(i, __float_as_int(di));
            if (i == n - 1) ptr[n] = excl + sl[j];
        }
        excl += sl[j];
    }
}

// ---------- fused scatter | gemm, stripe-interleaved for co-residency ----------
__global__ __launch_bounds__(256) void k_scatter_gemm(const int* __restrict__ ei,
                                                      int* __restrict__ cursor,
                                                      int2* __restrict__ srcW, int E,
                                                      const float* __restrict__ dinv,
                                                      const float* __restrict__ X,
                                                      const float* __restrict__ W,
                                                      __hip_bfloat16* __restrict__ Y,
                                                      int nrows) {
    int tid = threadIdx.x;
    int q = blockIdx.x / 3, k3 = blockIdx.x % 3;
    if (k3 < 2) {
        int e = (2 * q + k3) * 256 + tid;
        if (e < E) {
            int c = ei[(size_t)E + e];   // target
            int r = ei[e];               // source
            int pos = atomicAdd(&cursor[c], 1);
            srcW[pos] = make_int2(r, __float_as_int(dinv[r]));
        }
    } else {
        __shared__ float xsh[32][HDIM];
        int c = tid & 127;
        int g = tid >> 7;
        int r0 = q * 32;
        for (int idx = tid; idx < 32 * HDIM / 4; idx += 256) {
            int row = idx >> 5;
            int kk = (idx & 31) * 4;
            int gr = r0 + row;
            float4 v = make_float4(0.f, 0.f, 0.f, 0.f);
            if (gr < nrows) v = *(const float4*)(X + (size_t)gr * HDIM + kk);
            *(float4*)&xsh[row][kk] = v;
        }
        __syncthreads();
        float acc[16];
#pragma unroll
        for (int r = 0; r < 16; r++) acc[r] = 0.f;
        for (int k4 = 0; k4 < HDIM / 4; k4++) {
            int k = k4 * 4;
            float w0 = W[(size_t)(k + 0) * HDIM + c];
            float w1 = W[(size_t)(k + 1) * HDIM + c];
            float w2 = W[(size_t)(k + 2) * HDIM + c];
            float w3 = W[(size_t)(k + 3) * HDIM + c];
#pragma unroll
            for (int r = 0; r < 16; r++) {
                float4 xv = *(const float4*)&xsh[g * 16 + r][k];
                acc[r] = fmaf(xv.x, w0, fmaf(xv.y, w1, fmaf(xv.z, w2, fmaf(xv.w, w3, acc[r]))));
            }
        }
#pragma unroll
        for (int r = 0; r < 16; r++) {
            int gr = r0 + g * 16 + r;
            if (gr < nrows) Y[(size_t)gr * HDIM + c] = __float2bfloat16(acc[r]);
        }
    }
}

// ---------- bf16x8 unpack-FMA ----------
__device__ __forceinline__ void bf8_fma(uint4 qv, float w, float* acc) {
    unsigned u[4] = {qv.x, qv.y, qv.z, qv.w};
#pragma unroll
    for (int i = 0; i < 4; i++) {
        float lo = __uint_as_float(u[i] << 16);
        float hi = __uint_as_float(u[i] & 0xFFFF0000u);
        acc[2 * i]     = fmaf(w, lo, acc[2 * i]);
        acc[2 * i + 1] = fmaf(w, hi, acc[2 * i + 1]);
    }
}

// ---------- async-LDS agg pipeline over 8 contiguous nodes per wave ----------
// chunk = 16 slots. Per chunk: strip (16x int2 srcW, width-4 gld_lds) + 4x
// width-16 gld_lds row gathers (4 rows/instr, per-lane global addr, linear LDS
// dest -> conflict-free ds_read_b128 at consume). 3-stage pipeline, invariant
// at loop top: outstanding = {strip(c+1)[1], rows(c)[4]} (issue order!).
// vmcnt(4) retires strip(c+1); after issuing strip(c+2)+rows(c+1), vmcnt(5)
// (or 4 when no strip) retires rows(c). Tail chunk: vmcnt(0). All branch
// conditions wave-uniform.
template <typename F>
__device__ __forceinline__ void agg_nodes(const __hip_bfloat16* __restrict__ hin,
                                          const int* __restrict__ pptr,
                                          const int2* __restrict__ srcW,
                                          const float* __restrict__ dinv,
                                          const float* __restrict__ bias,
                                          char* __restrict__ my,
                                          int node0, int nA, int n, int lane,
                                          F&& emit) {
    const int fs = lane & 15, jg = lane >> 4;
    const int s0 = pptr[node0];
    const int nch = (pptr[node0 + nA] - s0) >> 4;

    auto issue_strip = [&](int c) {
        const int* ga = (const int*)(srcW + (size_t)(s0 + (c << 4))) + (lane & 31);
        gld_lds4(ga, my + RINGB + (c % 3) * 256);
    };
    auto issue_rows = [&](int c) {
        const char* strip = my + RINGB + (c % 3) * 256;
        int ids[4];
#pragma unroll
        for (int i = 0; i < 4; i++)
            ids[i] = *(const int*)(strip + (((i << 2) + jg) << 3));
        char* dst = my + (c & 1) * 4096;
#pragma unroll
        for (int i = 0; i < 4; i++) {
            const char* ga = (const char*)hin + ((size_t)(unsigned)ids[i] << 8) + (fs << 4);
            gld_lds16(ga, dst + i * 1024);
        }
    };

    // prologue
    issue_strip(0);
    vm_wait0();
    if (nch > 1) issue_strip(1);
    issue_rows(0);

    int c = 0;
    int pNext = pptr[node0 + 1];
    for (int k = 0; k < nA; ++k) {
        int pAfter = (node0 + k + 2 <= n) ? pptr[node0 + k + 2] : pNext;  // prefetch
        float diK = dinv[node0 + k];                                      // hoisted early
        float acc[8];
#pragma unroll
        for (int q = 0; q < 8; q++) acc[q] = 0.f;
        int ce = (pNext - s0) >> 4;
        for (; c < ce; ++c) {
            if (c + 1 < nch) {
                vm_wait4();                            // strip(c+1) landed
                if (c + 2 < nch) {
                    issue_strip(c + 2);                // strip BEFORE rows (retire order)
                    issue_rows(c + 1);
                    vm_wait5();                        // rows(c) landed
                } else {
                    issue_rows(c + 1);
                    vm_wait4();                        // rows(c) landed
                }
            } else {
                vm_wait0();                            // last chunk
            }
            const char* rowb  = my + (c & 1) * 4096;
            const char* strip = my + RINGB + (c % 3) * 256;
#pragma unroll
            for (int t = 0; t < 4; t++) {
                int sslot = (t << 2) + jg;
                float wgt = *(const float*)(strip + (sslot << 3) + 4);
                uint4 qv  = *(const uint4*)(rowb + (sslot << 8) + (fs << 4));
                bf8_fma(qv, wgt, acc);
            }
        }
#pragma unroll
        for (int q = 0; q < 8; q++) {
            acc[q] += __shfl_xor(acc[q], 16, 64);
            acc[q] += __shfl_xor(acc[q], 32, 64);
        }
        const float4* b4 = (const float4*)(bias + fs * 8);
        float4 bb0 = b4[0], bb1 = b4[1];
        float h[8];
        h[0] = fmaf(diK, acc[0], bb0.x); h[1] = fmaf(diK, acc[1], bb0.y);
        h[2] = fmaf(diK, acc[2], bb0.z); h[3] = fmaf(diK, acc[3], bb0.w);
        h[4] = fmaf(diK, acc[4], bb1.x); h[5] = fmaf(diK, acc[5], bb1.y);
        h[6] = fmaf(diK, acc[6], bb1.z); h[7] = fmaf(diK, acc[7], bb1.w);
        emit(k, h);
        pNext = pAfter;
    }
}

// ---------- fused agg layer-1 + GEMM layer-2 ----------
// Block = 32 nodes: phase 1 = 4 waves x 8 nodes async-agg -> h1 rows into xsh;
// phase 2 = GEMM reading xsh, W2 streamed, bf16 out. LDS 52224B -> 3 blk/CU.
__global__ __launch_bounds__(256) void k_agg_gemm(const __hip_bfloat16* __restrict__ hin,
                                                  __hip_bfloat16* __restrict__ hout,
                                                  const int* __restrict__ pptr,
                                                  const int2* __restrict__ srcW,
                                                  const float* __restrict__ dinv,
                                                  const float* __restrict__ bias,
                                                  const float* __restrict__ W2, int n) {
    __shared__ __align__(16) char smem[4 * WLDS];
    __shared__ float xsh[32][HDIM];
    int tid = threadIdx.x;
    int w = tid >> 6, lane = tid & 63;
    int fs = lane & 15, jg = lane >> 4;
    int node0 = blockIdx.x * 32 + w * 8;
    int nA = n - node0; nA = nA > 8 ? 8 : nA;
    char* my = smem + w * WLDS;

    if (nA > 0) {
        agg_nodes(hin, pptr, srcW, dinv, bias, my, node0, nA, n, lane,
                  [&](int k, const float* h) {
                      if (jg == 0) {
                          int lr = w * 8 + k;
                          *(float4*)&xsh[lr][fs * 8]     = make_float4(h[0], h[1], h[2], h[3]);
                          *(float4*)&xsh[lr][fs * 8 + 4] = make_float4(h[4], h[5], h[6], h[7]);
                      }
                  });
    }
    for (int k = (nA > 0 ? nA : 0); k < 8; ++k) {
        if (jg == 0) {
            float4 z = make_float4(0.f, 0.f, 0.f, 0.f);
            *(float4*)&xsh[w * 8 + k][fs * 8]     = z;
            *(float4*)&xsh[w * 8 + k][fs * 8 + 4] = z;
        }
    }
    __syncthreads();

    int c = tid & 127, g = tid >> 7;
    int base = blockIdx.x * 32;
    float acc[16];
#pragma unroll
    for (int r = 0; r < 16; r++) acc[r] = 0.f;
    for (int k4 = 0; k4 < HDIM / 4; k4++) {
        int k = k4 * 4;
        float w0 = W2[(size_t)(k + 0) * HDIM + c];
        float w1 = W2[(size_t)(k + 1) * HDIM + c];
        float w2 = W2[(size_t)(k + 2) * HDIM + c];
        float w3 = W2[(size_t)(k + 3) * HDIM + c];
#pragma unroll
        for (int r = 0; r < 16; r++) {
            float4 xv = *(const float4*)&xsh[g * 16 + r][k];
            acc[r] = fmaf(xv.x, w0, fmaf(xv.y, w1, fmaf(xv.z, w2, fmaf(xv.w, w3, acc[r]))));
        }
    }
#pragma unroll
    for (int r = 0; r < 16; r++) {
        int gr = base + g * 16 + r;
        if (gr < n) hout[(size_t)gr * HDIM + c] = __float2bfloat16(acc[r]);
    }
}

// ---------- agg layer 2 + fused FC ----------
// Same 8-nodes/wave async pipeline; epilogue = 128->8 FC. LDS 35840B -> 4 blk/CU.
__global__ __launch_bounds__(256) void k_agg_fc(const __hip_bfloat16* __restrict__ hin,
                                                const int* __restrict__ pptr,
                                                const int2* __restrict__ srcW,
                                                const float* __restrict__ dinv,
                                                const float* __restrict__ bias,
                                                const float* __restrict__ Wfc,
                                                const float* __restrict__ bfc,
                                                float* __restrict__ out, int n) {
    __shared__ __align__(16) char smem[4 * WLDS];
    int tid = threadIdx.x;
    int w = tid >> 6, lane = tid & 63;
    int fs = lane & 15, jg = lane >> 4;
    int node0 = blockIdx.x * 32 + w * 8;
    int nA = n - node0; nA = nA > 8 ? 8 : nA;
    if (nA <= 0) return;
    char* my = smem + w * WLDS;

    agg_nodes(hin, pptr, srcW, dinv, bias, my, node0, nA, n, lane,
              [&](int k, const float* h) {
                  // FC: lane covers outputs c0=2*jg, c0+1 over its 8 features; Wfc 4KB L1-hot
                  int c0 = jg * 2;
                  float p0 = 0.f, p1 = 0.f;
#pragma unroll
                  for (int kk = 0; kk < 8; kk++) {
                      const float* wr = Wfc + (size_t)(fs * 8 + kk) * CDIM + c0;
                      p0 = fmaf(h[kk], wr[0], p0);
                      p1 = fmaf(h[kk], wr[1], p1);
                  }
#pragma unroll
                  for (int off = 1; off < 16; off <<= 1) {
                      p0 += __shfl_xor(p0, off, 64);
                      p1 += __shfl_xor(p1, off, 64);
                  }
                  if (fs == 0) {
                      int node = node0 + k;
                      out[(size_t)node * CDIM + c0]     = p0 + bfc[c0];
                      out[(size_t)node * CDIM + c0 + 1] = p1 + bfc[c0 + 1];
                  }
              });
}

extern "C" void kernel_launch(void* const* d_in, const int* in_sizes, int n_in,
                              void* d_out, int out_size, void* d_ws, size_t ws_size,
                              hipStream_t stream) {
    const float* x   = (const float*)d_in[0];
    const int*   ei  = (const int*)d_in[1];
    const float* W1  = (const float*)d_in[2];
    const float* b1  = (const float*)d_in[3];
    const float* W2  = (const float*)d_in[4];
    const float* b2  = (const float*)d_in[5];
    const float* Wfc = (const float*)d_in[6];
    const float* bfc = (const float*)d_in[7];
    float* out = (float*)d_out;

    const int N = in_sizes[0] / HDIM;   // 50000
    const int E = in_sizes[1] / 2;      // 800000
    const int B = (N + SCAN_CHUNK - 1) / SCAN_CHUNK;   // 13

    // workspace layout (~39 MB): srcW now padded CSR, <= E + 16N slots
    __hip_bfloat16* bufH  = (__hip_bfloat16*)d_ws;                       // N*128 bf16
    __hip_bfloat16* bufH2 = bufH + (size_t)N * HDIM;                     // N*128 bf16
    float* dinv   = (float*)(bufH2 + (size_t)N * HDIM);  // N
    int*   cnt    = (int*)(dinv + N);                    // N      } zeroed together
    int*   status = cnt + N;                             // 16     }
    int*   ptr    = status + 16;                         // N+1 (padded slot offsets)
    int*   cursor = ptr + (N + 1);                       // N
    int2*  srcW   = (int2*)(((uintptr_t)(cursor + N) + 15) & ~(uintptr_t)15);

    hipMemsetAsync(cnt, 0, (size_t)(N + 16) * sizeof(int), stream);
    hipMemsetAsync(srcW, 0, ((size_t)E + 16 * (size_t)N + 64) * sizeof(int2), stream);
    k_hist<<<(E + 255) / 256, 256, 0, stream>>>(ei + E, cnt, E);
    k_scan<<<B, 256, 0, stream>>>(cnt, status, ptr, cursor, dinv, srcW, N);

    const int Gg = (N + 31) / 32;          // 1563 blocks; 2*Gg=3126 >= 3125 scatter
    k_scatter_gemm<<<3 * Gg, 256, 0, stream>>>(ei, cursor, srcW, E, dinv, x, W1, bufH, N);

    k_agg_gemm<<<Gg, 256, 0, stream>>>(bufH, bufH2, ptr, srcW, dinv, b1, W2, N);
    k_agg_fc<<<Gg, 256, 0, stream>>>(bufH2, ptr, srcW, dinv, b2, Wfc, bfc, out, N);
}

// Round 2
// 306.971 us; speedup vs baseline: 1.1606x; 1.1606x over previous
//
#include <hip/hip_runtime.h>
#include <hip/hip_bf16.h>

#define HDIM 128
#define CDIM 8
#define SCAN_CHUNK 4096   // 256 threads x 16 elements

// Harness contract (pinned empirically, rounds 1-3):
//   float32 tensors -> const float* ; int64 edge_index -> const int* ; output -> float*
//
// R13 post-mortem of R12: async gld_lds pipeline RAISED per-slot gather
// throughput 2.6->3.2 TB/s, but per-node 16-padding inflated slots 1.44x and
// LDS 52KB cut occupancy to 3 blk/CU -> net regression. R13 keeps the
// pipeline, fixes both losing terms: (a) PAIR-padded CSR (2 nodes/segment,
// one pad -> 1.19x inflation), consume splits chunks at the pair boundary
// into accA/accB; (b) xsh overlaid on dead agg rings via 2-float/lane h
// buffering -> LDS 35840, 4 blk/CU, launch_bounds(256,4).

#define WLDS  8960        // per-wave LDS: 2*4096B row ring + 3*256B strip ring
#define RINGB 8192

__device__ __forceinline__ void vm_wait0() { asm volatile("s_waitcnt vmcnt(0)" ::: "memory"); }
__device__ __forceinline__ void vm_wait4() { asm volatile("s_waitcnt vmcnt(4)" ::: "memory"); }
__device__ __forceinline__ void vm_wait5() { asm volatile("s_waitcnt vmcnt(5)" ::: "memory"); }

__device__ __forceinline__ void gld_lds16(const void* g, void* s) {
    __builtin_amdgcn_global_load_lds((const __attribute__((address_space(1))) void*)g,
                                     (__attribute__((address_space(3))) void*)s, 16, 0, 0);
}
__device__ __forceinline__ void gld_lds4(const void* g, void* s) {
    __builtin_amdgcn_global_load_lds((const __attribute__((address_space(1))) void*)g,
                                     (__attribute__((address_space(3))) void*)s, 4, 0, 0);
}

// ---------- histogram ----------
__global__ void k_hist(const int* __restrict__ col, int* __restrict__ cnt, int E) {
    int e = blockIdx.x * blockDim.x + threadIdx.x;
    if (e < E) atomicAdd(&cnt[col[e]], 1);
}

// ---------- scan over PAIR-padded slot counts ----------
// pair p = nodes (2p, 2p+1): T = dA+dB+2 logical slots (self-loops at local
// 0 and dA+1), padded P = ceil(T/16)*16, pad slots stay memset (0, 0.0f) =
// row-0 gather with weight 0 (exact no-op, routed to node B).
// ptr[even] = segment start (16-aligned); ptr[odd] = B's logical start.
__global__ __launch_bounds__(256) void k_scan(const int* __restrict__ cnt,
                                              int* __restrict__ status,
                                              int* __restrict__ ptr,
                                              int* __restrict__ cursor,
                                              float* __restrict__ dinv,
                                              int2* __restrict__ srcW,
                                              int n) {
    int b = blockIdx.x, tid = threadIdx.x;
    int base = b * SCAN_CHUNK + tid * 16;   // 16 nodes = 8 pairs per thread
    int v[16], P[8];
    int s = 0;
#pragma unroll
    for (int j = 0; j < 16; j++) {
        int i = base + j;
        v[j] = (i < n) ? cnt[i] : 0;
    }
#pragma unroll
    for (int p = 0; p < 8; p++) {
        int iA = base + 2 * p;
        int T = v[2 * p] + v[2 * p + 1] + 2;
        P[p] = (iA < n) ? ((T + 15) & ~15) : 0;
        s += P[p];
    }
    int lane = tid & 63, wid = tid >> 6;
    int x = s;
    for (int off = 1; off < 64; off <<= 1) {
        int y = __shfl_up(x, off, 64);
        if (lane >= off) x += y;
    }
    __shared__ int wtot[4];
    __shared__ int sprefix;
    if (lane == 63) wtot[wid] = x;
    __syncthreads();
    if (tid == 0) {
        int tot = wtot[0] + wtot[1] + wtot[2] + wtot[3];
        atomicExch(&status[b], tot + 1);            // publish first (no peer deadlock)
        int pre = 0;
        for (int p = 0; p < b; p++) {
            int vv;
            do { vv = atomicAdd(&status[p], 0); } while (vv == 0);
            pre += vv - 1;
        }
        sprefix = pre;
    }
    __syncthreads();
    int woff = 0;
    for (int w = 0; w < wid; w++) woff += wtot[w];
    int excl = sprefix + woff + (x - s);
#pragma unroll
    for (int p = 0; p < 8; p++) {
        int iA = base + 2 * p, iB = iA + 1;
        if (iA < n) {                                 // n even: iA,iB together
            int vA = v[2 * p], vB = v[2 * p + 1];
            ptr[iA] = excl;
            ptr[iB] = excl + vA + 1;
            cursor[iA] = excl + 1;                    // past self A
            cursor[iB] = excl + vA + 2;               // past self B
            float dA = rsqrtf((float)vA + 1.0f);
            float dB = rsqrtf((float)vB + 1.0f);
            dinv[iA] = dA; dinv[iB] = dB;
            srcW[excl]          = make_int2(iA, __float_as_int(dA));
            srcW[excl + vA + 1] = make_int2(iB, __float_as_int(dB));
            if (iB == n - 1) ptr[n] = excl + P[p];
        }
        excl += P[p];
    }
}

// ---------- fused scatter | gemm, stripe-interleaved for co-residency ----------
__global__ __launch_bounds__(256) void k_scatter_gemm(const int* __restrict__ ei,
                                                      int* __restrict__ cursor,
                                                      int2* __restrict__ srcW, int E,
                                                      const float* __restrict__ dinv,
                                                      const float* __restrict__ X,
                                                      const float* __restrict__ W,
                                                      __hip_bfloat16* __restrict__ Y,
                                                      int nrows) {
    int tid = threadIdx.x;
    int q = blockIdx.x / 3, k3 = blockIdx.x % 3;
    if (k3 < 2) {
        int e = (2 * q + k3) * 256 + tid;
        if (e < E) {
            int c = ei[(size_t)E + e];   // target
            int r = ei[e];               // source
            int pos = atomicAdd(&cursor[c], 1);
            srcW[pos] = make_int2(r, __float_as_int(dinv[r]));
        }
    } else {
        __shared__ float xsh[32][HDIM];
        int c = tid & 127;
        int g = tid >> 7;
        int r0 = q * 32;
        for (int idx = tid; idx < 32 * HDIM / 4; idx += 256) {
            int row = idx >> 5;
            int kk = (idx & 31) * 4;
            int gr = r0 + row;
            float4 v = make_float4(0.f, 0.f, 0.f, 0.f);
            if (gr < nrows) v = *(const float4*)(X + (size_t)gr * HDIM + kk);
            *(float4*)&xsh[row][kk] = v;
        }
        __syncthreads();
        float acc[16];
#pragma unroll
        for (int r = 0; r < 16; r++) acc[r] = 0.f;
        for (int k4 = 0; k4 < HDIM / 4; k4++) {
            int k = k4 * 4;
            float w0 = W[(size_t)(k + 0) * HDIM + c];
            float w1 = W[(size_t)(k + 1) * HDIM + c];
            float w2 = W[(size_t)(k + 2) * HDIM + c];
            float w3 = W[(size_t)(k + 3) * HDIM + c];
#pragma unroll
            for (int r = 0; r < 16; r++) {
                float4 xv = *(const float4*)&xsh[g * 16 + r][k];
                acc[r] = fmaf(xv.x, w0, fmaf(xv.y, w1, fmaf(xv.z, w2, fmaf(xv.w, w3, acc[r]))));
            }
        }
#pragma unroll
        for (int r = 0; r < 16; r++) {
            int gr = r0 + g * 16 + r;
            if (gr < nrows) Y[(size_t)gr * HDIM + c] = __float2bfloat16(acc[r]);
        }
    }
}

// ---------- bf16x8 unpack-FMA ----------
__device__ __forceinline__ void bf8_fma(uint4 qv, float w, float* acc) {
    unsigned u[4] = {qv.x, qv.y, qv.z, qv.w};
#pragma unroll
    for (int i = 0; i < 4; i++) {
        float lo = __uint_as_float(u[i] << 16);
        float hi = __uint_as_float(u[i] & 0xFFFF0000u);
        acc[2 * i]     = fmaf(w, lo, acc[2 * i]);
        acc[2 * i + 1] = fmaf(w, hi, acc[2 * i + 1]);
    }
}

// ---------- async-LDS agg pipeline: 8 nodes = 4 pair-segments per wave ----------
// chunk = 16 slots. Per chunk: strip (16x int2 srcW, width-4 gld_lds) + 4x
// width-16 gld_lds row gathers. 3-stage pipeline, invariant at loop top:
// outstanding = {strip(c+1)[1], rows(c)[4]} in issue order. vmcnt(4) retires
// strip(c+1); after strip(c+2)+rows(c+1), vmcnt(5) (or 4 w/o strip) retires
// rows(c). Tail: vmcnt(0). Pair boundary routes slot rel<bAo -> accA else
// accB (divergent for <=1 t-group per pair). All waits wave-uniform.
template <typename F>
__device__ __forceinline__ void agg_nodes(const __hip_bfloat16* __restrict__ hin,
                                          const int* __restrict__ pptr,
                                          const int2* __restrict__ srcW,
                                          const float* __restrict__ dinv,
                                          const float* __restrict__ bias,
                                          char* __restrict__ my,
                                          int node0, int nA, int lane,
                                          F&& emit) {
    const int fs = lane & 15, jg = lane >> 4;
    const int s0 = pptr[node0];
    const int nch = (pptr[node0 + nA] - s0) >> 4;
    // lane-parallel pair metadata: lane l<8 holds ptr[node0+l+1], dinv[node0+l]
    int   myp  = pptr[node0 + (lane & 7) + 1];
    float mydv = dinv[node0 + (lane & 7)];
    const float4* b4 = (const float4*)(bias + fs * 8);
    const float4 bb0 = b4[0], bb1 = b4[1];

    auto issue_strip = [&](int c) {
        const int* ga = (const int*)(srcW + (size_t)(s0 + (c << 4))) + (lane & 31);
        gld_lds4(ga, my + RINGB + (c % 3) * 256);
    };
    auto issue_rows = [&](int c) {
        const char* strip = my + RINGB + (c % 3) * 256;
        int ids[4];
#pragma unroll
        for (int i = 0; i < 4; i++)
            ids[i] = *(const int*)(strip + (((i << 2) + jg) << 3));
        char* dst = my + (c & 1) * 4096;
#pragma unroll
        for (int i = 0; i < 4; i++) {
            const char* ga = (const char*)hin + ((size_t)(unsigned)ids[i] << 8) + (fs << 4);
            gld_lds16(ga, dst + i * 1024);
        }
    };

    // prologue
    issue_strip(0);
    vm_wait0();
    if (nch > 1) issue_strip(1);
    issue_rows(0);

    int c = 0;
    const int npair = nA >> 1;
#pragma unroll 4
    for (int kp = 0; kp < 4; ++kp) {
        if (kp >= npair) break;
        const int bAo = __shfl(myp, 2 * kp, 64) - s0;          // B logical start (rel)
        const int ce  = (__shfl(myp, 2 * kp + 1, 64) - s0) >> 4; // next pair start /16
        const float diA = __shfl(mydv, 2 * kp, 64);
        const float diB = __shfl(mydv, 2 * kp + 1, 64);
        float accA[8], accB[8];
#pragma unroll
        for (int q = 0; q < 8; q++) { accA[q] = 0.f; accB[q] = 0.f; }
        for (; c < ce; ++c) {
            if (c + 1 < nch) {
                vm_wait4();                            // strip(c+1) landed
                if (c + 2 < nch) {
                    issue_strip(c + 2);                // strip BEFORE rows (retire order)
                    issue_rows(c + 1);
                    vm_wait5();                        // rows(c) landed
                } else {
                    issue_rows(c + 1);
                    vm_wait4();                        // rows(c) landed
                }
            } else {
                vm_wait0();                            // last chunk
            }
            const char* rowb  = my + (c & 1) * 4096;
            const char* strip = my + RINGB + (c % 3) * 256;
#pragma unroll
            for (int t = 0; t < 4; t++) {
                int sslot = (t << 2) + jg;
                int rel = (c << 4) + sslot;
                float wgt = *(const float*)(strip + (sslot << 3) + 4);
                uint4 qv  = *(const uint4*)(rowb + (sslot << 8) + (fs << 4));
                if (rel < bAo) bf8_fma(qv, wgt, accA);
                else           bf8_fma(qv, wgt, accB);
            }
        }
        // finish node A then node B
#pragma unroll
        for (int q = 0; q < 8; q++) {
            accA[q] += __shfl_xor(accA[q], 16, 64);
            accA[q] += __shfl_xor(accA[q], 32, 64);
            accB[q] += __shfl_xor(accB[q], 16, 64);
            accB[q] += __shfl_xor(accB[q], 32, 64);
        }
        {
            float h[8];
            h[0] = fmaf(diA, accA[0], bb0.x); h[1] = fmaf(diA, accA[1], bb0.y);
            h[2] = fmaf(diA, accA[2], bb0.z); h[3] = fmaf(diA, accA[3], bb0.w);
            h[4] = fmaf(diA, accA[4], bb1.x); h[5] = fmaf(diA, accA[5], bb1.y);
            h[6] = fmaf(diA, accA[6], bb1.z); h[7] = fmaf(diA, accA[7], bb1.w);
            emit(2 * kp, h);
        }
        {
            float h[8];
            h[0] = fmaf(diB, accB[0], bb0.x); h[1] = fmaf(diB, accB[1], bb0.y);
            h[2] = fmaf(diB, accB[2], bb0.z); h[3] = fmaf(diB, accB[3], bb0.w);
            h[4] = fmaf(diB, accB[4], bb1.x); h[5] = fmaf(diB, accB[5], bb1.y);
            h[6] = fmaf(diB, accB[6], bb1.z); h[7] = fmaf(diB, accB[7], bb1.w);
            emit(2 * kp + 1, h);
        }
    }
}

// ---------- fused agg layer-1 + GEMM layer-2 ----------
// Phase 1: 4 waves x 8 nodes async-agg, h buffered 2 floats/lane (feature
// 8fs+2jg+{0,1}). Phase 2: xsh OVERLAYS the dead rings (barrier-separated),
// GEMM reads xsh, W2 streamed. LDS 35840 -> 4 blk/CU.
__global__ __launch_bounds__(256, 4) void k_agg_gemm(const __hip_bfloat16* __restrict__ hin,
                                                     __hip_bfloat16* __restrict__ hout,
                                                     const int* __restrict__ pptr,
                                                     const int2* __restrict__ srcW,
                                                     const float* __restrict__ dinv,
                                                     const float* __restrict__ bias,
                                                     const float* __restrict__ W2, int n) {
    __shared__ __align__(16) char smem[4 * WLDS];
    int tid = threadIdx.x;
    int w = tid >> 6, lane = tid & 63;
    int fs = lane & 15, jg = lane >> 4;
    int node0 = blockIdx.x * 32 + w * 8;
    int nA = n - node0; nA = nA > 8 ? 8 : nA;
    char* my = smem + w * WLDS;

    float hA[8], hB[8];
#pragma unroll
    for (int k = 0; k < 8; k++) { hA[k] = 0.f; hB[k] = 0.f; }

    if (nA > 0) {
        agg_nodes(hin, pptr, srcW, dinv, bias, my, node0, nA, lane,
                  [&](int k, const float* h) {
                      // keep features 8fs+2jg+{0,1}: static select tree on jg
                      float lo = (jg & 2) ? ((jg & 1) ? h[6] : h[4])
                                          : ((jg & 1) ? h[2] : h[0]);
                      float hi = (jg & 2) ? ((jg & 1) ? h[7] : h[5])
                                          : ((jg & 1) ? h[3] : h[1]);
                      hA[k] = lo; hB[k] = hi;     // k is constexpr at call site
                  });
    }
    __syncthreads();                               // all aggs done; rings dead

    float (*xsh)[HDIM] = (float(*)[HDIM])smem;     // overlay
    int f = fs * 8 + jg * 2;
#pragma unroll
    for (int k = 0; k < 8; k++)
        *(float2*)&xsh[w * 8 + k][f] = make_float2(hA[k], hB[k]);
    __syncthreads();

    int c = tid & 127, g = tid >> 7;
    int base = blockIdx.x * 32;
    float acc[16];
#pragma unroll
    for (int r = 0; r < 16; r++) acc[r] = 0.f;
    for (int k4 = 0; k4 < HDIM / 4; k4++) {
        int k = k4 * 4;
        float w0 = W2[(size_t)(k + 0) * HDIM + c];
        float w1 = W2[(size_t)(k + 1) * HDIM + c];
        float w2 = W2[(size_t)(k + 2) * HDIM + c];
        float w3 = W2[(size_t)(k + 3) * HDIM + c];
#pragma unroll
        for (int r = 0; r < 16; r++) {
            float4 xv = *(const float4*)&xsh[g * 16 + r][k];
            acc[r] = fmaf(xv.x, w0, fmaf(xv.y, w1, fmaf(xv.z, w2, fmaf(xv.w, w3, acc[r]))));
        }
    }
#pragma unroll
    for (int r = 0; r < 16; r++) {
        int gr = base + g * 16 + r;
        if (gr < n) hout[(size_t)gr * HDIM + c] = __float2bfloat16(acc[r]);
    }
}

// ---------- agg layer 2 + fused FC ----------
__global__ __launch_bounds__(256, 4) void k_agg_fc(const __hip_bfloat16* __restrict__ hin,
                                                   const int* __restrict__ pptr,
                                                   const int2* __restrict__ srcW,
                                                   const float* __restrict__ dinv,
                                                   const float* __restrict__ bias,
                                                   const float* __restrict__ Wfc,
                                                   const float* __restrict__ bfc,
                                                   float* __restrict__ out, int n) {
    __shared__ __align__(16) char smem[4 * WLDS];
    int tid = threadIdx.x;
    int w = tid >> 6, lane = tid & 63;
    int fs = lane & 15, jg = lane >> 4;
    int node0 = blockIdx.x * 32 + w * 8;
    int nA = n - node0; nA = nA > 8 ? 8 : nA;
    if (nA <= 0) return;
    char* my = smem + w * WLDS;

    agg_nodes(hin, pptr, srcW, dinv, bias, my, node0, nA, lane,
              [&](int k, const float* h) {
                  // FC: lane covers outputs c0=2*jg, c0+1 over its 8 features; Wfc 4KB L1-hot
                  int c0 = jg * 2;
                  float p0 = 0.f, p1 = 0.f;
#pragma unroll
                  for (int kk = 0; kk < 8; kk++) {
                      const float* wr = Wfc + (size_t)(fs * 8 + kk) * CDIM + c0;
                      p0 = fmaf(h[kk], wr[0], p0);
                      p1 = fmaf(h[kk], wr[1], p1);
                  }
#pragma unroll
                  for (int off = 1; off < 16; off <<= 1) {
                      p0 += __shfl_xor(p0, off, 64);
                      p1 += __shfl_xor(p1, off, 64);
                  }
                  if (fs == 0) {
                      int node = node0 + k;
                      out[(size_t)node * CDIM + c0]     = p0 + bfc[c0];
                      out[(size_t)node * CDIM + c0 + 1] = p1 + bfc[c0 + 1];
                  }
              });
}

extern "C" void kernel_launch(void* const* d_in, const int* in_sizes, int n_in,
                              void* d_out, int out_size, void* d_ws, size_t ws_size,
                              hipStream_t stream) {
    const float* x   = (const float*)d_in[0];
    const int*   ei  = (const int*)d_in[1];
    const float* W1  = (const float*)d_in[2];
    const float* b1  = (const float*)d_in[3];
    const float* W2  = (const float*)d_in[4];
    const float* b2  = (const float*)d_in[5];
    const float* Wfc = (const float*)d_in[6];
    const float* bfc = (const float*)d_in[7];
    float* out = (float*)d_out;

    const int N = in_sizes[0] / HDIM;   // 50000
    const int E = in_sizes[1] / 2;      // 800000
    const int B = (N + SCAN_CHUNK - 1) / SCAN_CHUNK;   // 13

    // workspace layout (~37 MB): srcW pair-padded CSR, <= E + 8N slots
    __hip_bfloat16* bufH  = (__hip_bfloat16*)d_ws;                       // N*128 bf16
    __hip_bfloat16* bufH2 = bufH + (size_t)N * HDIM;                     // N*128 bf16
    float* dinv   = (float*)(bufH2 + (size_t)N * HDIM);  // N
    int*   cnt    = (int*)(dinv + N);                    // N      } zeroed together
    int*   status = cnt + N;                             // 16     }
    int*   ptr    = status + 16;                         // N+1 (pair-padded offsets)
    int*   cursor = ptr + (N + 1);                       // N
    int2*  srcW   = (int2*)(((uintptr_t)(cursor + N) + 15) & ~(uintptr_t)15);

    hipMemsetAsync(cnt, 0, (size_t)(N + 16) * sizeof(int), stream);
    hipMemsetAsync(srcW, 0, ((size_t)E + 9 * (size_t)N + 64) * sizeof(int2), stream);
    k_hist<<<(E + 255) / 256, 256, 0, stream>>>(ei + E, cnt, E);
    k_scan<<<B, 256, 0, stream>>>(cnt, status, ptr, cursor, dinv, srcW, N);

    const int Gg = (N + 31) / 32;          // 1563 blocks; 2*Gg=3126 >= 3125 scatter
    k_scatter_gemm<<<3 * Gg, 256, 0, stream>>>(ei, cursor, srcW, E, dinv, x, W1, bufH, N);

    k_agg_gemm<<<Gg, 256, 0, stream>>>(bufH, bufH2, ptr, srcW, dinv, b1, W2, N);
    k_agg_fc<<<Gg, 256, 0, stream>>>(bufH2, ptr, srcW, dinv, b2, Wfc, bfc, out, N);
}